// Round 1
// baseline (229.071 us; speedup 1.0000x reference)
//
#include <hip/hip_runtime.h>
#include <math.h>

#define D 128
#define EPS 1e-7f

typedef unsigned int uint;

__device__ __forceinline__ int sdot4(int a, int b, int c) {
#if __has_builtin(__builtin_amdgcn_sdot4)
    return __builtin_amdgcn_sdot4(a, b, c, false);   // v_dot4_i32_i8
#else
    int r = c;
    #pragma unroll
    for (int i = 0; i < 4; ++i) {
        int av = (a << (24 - 8 * i)) >> 24;
        int bv = (b << (24 - 8 * i)) >> 24;
        r += av * bv;
    }
    return r;
#endif
}

// ---------------- Fused persistent kernel ----------------
// Phase 1: per-node precompute (identical math to verified 2-kernel version):
//   m[n] = z[n]·W + b; q[n] = round(z[n]/s_n) int8 (row = 128 B);
//   meta[n] = {s_n, s_n^2·Σq², m_n, 0}. 32 lanes/node, 2 nodes/wave-iter.
// Grid barrier: manual device-scope barrier (counter in ws, memset to 0 by
//   host each launch). Release = __threadfence (agent wbl2) + atomicAdd;
//   acquire = agent-scope atomic load (buffer_inv) → cross-XCD visibility
//   of zq/meta per G16. 1024 blocks @ 256 thr, __launch_bounds__(256,4):
//   4 blocks/CU co-resident by construction (LDS=0, VGPR<=128) -> no deadlock.
// Phase 2: per-edge, 4 lanes/edge, 16 edges/wave-iter. Cross-dot exact i32
//   via sdot4; dist2 = nrm_i + nrm_j − 2·si·sj·dot (==0 exactly when src==dst).
// R11 theory: two-launch + kernel-boundary drain is ~10-20 us of the 117.7;
//   phases are each well under the 43 us poison-fills (absent from top-5).
__global__ __launch_bounds__(256, 4) void fused_gravity(
    const float* __restrict__ z, const float* __restrict__ W,
    const float* __restrict__ b, const int* __restrict__ ei,
    float* __restrict__ out, uint* __restrict__ zq,
    float4* __restrict__ meta, uint* __restrict__ bar,
    int N, int E, int nblocks)
{
    const int lane = threadIdx.x & 63;
    const int wid  = blockIdx.x * (blockDim.x >> 6) + (threadIdx.x >> 6);
    const int nw   = nblocks * (blockDim.x >> 6);

    // ---------- phase 1: nodes, grid-stride, 2 per wave-iter ----------
    {
        const int half = lane >> 5, sub = lane & 31;
        const float4 w4 = ((const float4*)W)[sub];   // hoisted: same every node
        const float bb = b[0];
        for (int n = wid * 2 + half; n < N; n += nw * 2) {
            const float4 a = ((const float4*)(z + (size_t)n * D))[sub];

            float dot = a.x * w4.x + a.y * w4.y + a.z * w4.z + a.w * w4.w;
            float amax = fmaxf(fmaxf(fabsf(a.x), fabsf(a.y)),
                               fmaxf(fabsf(a.z), fabsf(a.w)));
            #pragma unroll
            for (int off = 16; off > 0; off >>= 1) {
                dot  += __shfl_xor(dot, off);
                amax  = fmaxf(amax, __shfl_xor(amax, off));
            }

            const float s   = amax * (1.0f / 127.0f);
            const float inv = 127.0f / fmaxf(amax, 1e-30f);

            const int q0 = (int)rintf(fminf(fmaxf(a.x * inv, -127.f), 127.f));
            const int q1 = (int)rintf(fminf(fmaxf(a.y * inv, -127.f), 127.f));
            const int q2 = (int)rintf(fminf(fmaxf(a.z * inv, -127.f), 127.f));
            const int q3 = (int)rintf(fminf(fmaxf(a.w * inv, -127.f), 127.f));
            const uint pack = (uint)(q0 & 255) | ((uint)(q1 & 255) << 8)
                            | ((uint)(q2 & 255) << 16) | ((uint)q3 << 24);
            zq[(size_t)n * 32 + sub] = pack;

            int S = sdot4((int)pack, (int)pack, 0);
            #pragma unroll
            for (int off = 16; off > 0; off >>= 1) S += __shfl_xor(S, off);

            if (sub == 0) {
                float4 mt;
                mt.x = s;
                mt.y = (s * s) * (float)S;
                mt.z = dot + bb;
                mt.w = 0.f;
                meta[n] = mt;
            }
        }
    }

    // ---------- grid barrier (single-use per launch; bar starts at 0) ----------
    __syncthreads();
    if (threadIdx.x == 0) {
        __threadfence();  // agent-scope release: flush dirty zq/meta out of XCD L2
        __hip_atomic_fetch_add(bar, 1u, __ATOMIC_ACQ_REL, __HIP_MEMORY_SCOPE_AGENT);
        while (__hip_atomic_load(bar, __ATOMIC_ACQUIRE, __HIP_MEMORY_SCOPE_AGENT)
               < (uint)nblocks) {
            __builtin_amdgcn_s_sleep(2);
        }
    }
    __syncthreads();

    // ---------- phase 2: edges, grid-stride, 16 per wave-iter ----------
    {
        const int sub = lane & 3;
        const int g   = lane >> 2;
        for (int e = wid * 16 + g; e < E; e += nw * 16) {
            const int src = ei[e];
            const int dst = ei[E + e];

            const float4 Mi = meta[src];
            const float4 Mj = meta[dst];

            const uint4* ri = (const uint4*)(zq + (size_t)src * 32);
            const uint4* rj = (const uint4*)(zq + (size_t)dst * 32);
            const uint4 a0 = ri[sub];
            const uint4 a1 = ri[sub + 4];
            const uint4 c0 = rj[sub];
            const uint4 c1 = rj[sub + 4];

            int dot = sdot4((int)a0.x, (int)c0.x, 0);
            dot = sdot4((int)a0.y, (int)c0.y, dot);
            dot = sdot4((int)a0.z, (int)c0.z, dot);
            dot = sdot4((int)a0.w, (int)c0.w, dot);
            dot = sdot4((int)a1.x, (int)c1.x, dot);
            dot = sdot4((int)a1.y, (int)c1.y, dot);
            dot = sdot4((int)a1.z, (int)c1.z, dot);
            dot = sdot4((int)a1.w, (int)c1.w, dot);

            dot += __shfl_xor(dot, 1);
            dot += __shfl_xor(dot, 2);

            if (sub == 0) {
                const float wc = (Mi.x * Mj.x) * (float)dot;
                const float dist2 = fmaxf(Mi.y + Mj.y - wc - wc, 0.0f) + EPS;
                const float logits = Mj.z - __logf(dist2);
                const float prob   = 1.0f / (1.0f + __expf(-logits));
                out[e]         = logits;
                out[E + e]     = prob;
                out[2 * E + e] = Mj.z;
                out[3 * E + e] = dist2;
            }
        }
    }
}

// ---------------- Fallback if ws too small ----------------
__global__ __launch_bounds__(256) void gravity_decoder_fallback(
    const float* __restrict__ z, const int* __restrict__ ei,
    const float* __restrict__ W, const float* __restrict__ b,
    float* __restrict__ out, int E)
{
    const int lane = threadIdx.x & 63;
    const int half = lane >> 5, sub = lane & 31;
    const int e = (blockIdx.x * (blockDim.x >> 6) + (threadIdx.x >> 6)) * 2 + half;
    if (e >= E) return;
    const int src = ei[e], dst = ei[E + e];
    const float4* z4 = (const float4*)z;
    const float4 a = z4[(size_t)src * (D / 4) + sub];
    const float4 c = z4[(size_t)dst * (D / 4) + sub];
    const float4 w = ((const float4*)W)[sub];
    float dot = c.x * w.x + c.y * w.y + c.z * w.z + c.w * w.w;
    const float dx = a.x - c.x, dy = a.y - c.y, dz = a.z - c.z, dw = a.w - c.w;
    float d2 = dx * dx + dy * dy + dz * dz + dw * dw;
    #pragma unroll
    for (int off = 16; off > 0; off >>= 1) {
        dot += __shfl_xor(dot, off);
        d2  += __shfl_xor(d2,  off);
    }
    if (sub == 0) {
        const float mj = dot + b[0];
        const float dist2 = d2 + EPS;
        const float logits = mj - __logf(dist2);
        const float prob = 1.0f / (1.0f + __expf(-logits));
        out[e] = logits; out[E + e] = prob;
        out[2 * E + e] = mj; out[3 * E + e] = dist2;
    }
}

extern "C" void kernel_launch(void* const* d_in, const int* in_sizes, int n_in,
                              void* d_out, int out_size, void* d_ws, size_t ws_size,
                              hipStream_t stream)
{
    const float* z  = (const float*)d_in[0];
    const int*   ei = (const int*)d_in[1];
    const float* W  = (const float*)d_in[2];
    const float* b  = (const float*)d_in[3];
    float* out = (float*)d_out;

    const int E = in_sizes[1] / 2;   // edge_index is [2, E]
    const int N = in_sizes[0] / D;   // z is [N, 128]

    const size_t zq_bytes   = (size_t)N * D;              // i8 rows, 128 B
    const size_t meta_bytes = (size_t)N * sizeof(float4);
    const size_t bar_off    = zq_bytes + meta_bytes;

    if (ws_size >= bar_off + 64) {
        uint*   zq   = (uint*)d_ws;
        float4* meta = (float4*)((char*)d_ws + zq_bytes);
        uint*   bar  = (uint*)((char*)d_ws + bar_off);

        // Zero the barrier counter every launch (ws is poisoned between iters).
        // hipMemsetAsync is graph-capture-safe (becomes a memset node).
        hipMemsetAsync(bar, 0, sizeof(uint), stream);

        const int grid = 1024;  // 4 blocks/CU x 256 CUs, co-resident by launch_bounds
        fused_gravity<<<grid, 256, 0, stream>>>(z, W, b, ei, out, zq, meta, bar,
                                                N, E, grid);
    } else {
        const int edges_per_block = 8;
        gravity_decoder_fallback<<<(E + edges_per_block - 1) / edges_per_block,
                                   256, 0, stream>>>(z, ei, W, b, out, E);
    }
}

// Round 2
// 122.533 us; speedup vs baseline: 1.8695x; 1.8695x over previous
//
#include <hip/hip_runtime.h>
#include <math.h>

#define D 128
#define EPS 1e-7f

typedef unsigned int uint;

__device__ __forceinline__ int sdot4(int a, int b, int c) {
#if __has_builtin(__builtin_amdgcn_sdot4)
    return __builtin_amdgcn_sdot4(a, b, c, false);   // v_dot4_i32_i8
#else
    int r = c;
    #pragma unroll
    for (int i = 0; i < 4; ++i) {
        int av = (a << (24 - 8 * i)) >> 24;
        int bv = (b << (24 - 8 * i)) >> 24;
        r += av * bv;
    }
    return r;
#endif
}

// ---------------- Kernel 1: per-node precompute (unchanged, verified) -------
// m[n] = z[n]·W + b (exact f32). q[n] = round(z[n]/s_n) int8, s_n = rowmax/127.
// meta[n] = {s_n, nrm_n = s_n^2·Σq², m_n, 0}. 32 lanes/node, 2 nodes/wave.
__global__ __launch_bounds__(256) void node_precompute_kernel(
    const float* __restrict__ z, const float* __restrict__ W,
    const float* __restrict__ b,
    uint* __restrict__ zq,        // [N, 32] dwords (128 i8 per row)
    float4* __restrict__ meta, int N)
{
    const int lane = threadIdx.x & 63;
    const int half = lane >> 5, sub = lane & 31;
    const int n = (blockIdx.x * (blockDim.x >> 6) + (threadIdx.x >> 6)) * 2 + half;
    if (n >= N) return;

    const float4 a = ((const float4*)(z + (size_t)n * D))[sub];
    const float4 w = ((const float4*)W)[sub];

    float dot = a.x * w.x + a.y * w.y + a.z * w.z + a.w * w.w;
    float amax = fmaxf(fmaxf(fabsf(a.x), fabsf(a.y)), fmaxf(fabsf(a.z), fabsf(a.w)));
    #pragma unroll
    for (int off = 16; off > 0; off >>= 1) {
        dot  += __shfl_xor(dot, off);
        amax  = fmaxf(amax, __shfl_xor(amax, off));
    }

    const float s   = amax * (1.0f / 127.0f);
    const float inv = 127.0f / fmaxf(amax, 1e-30f);

    const int q0 = (int)rintf(fminf(fmaxf(a.x * inv, -127.f), 127.f));
    const int q1 = (int)rintf(fminf(fmaxf(a.y * inv, -127.f), 127.f));
    const int q2 = (int)rintf(fminf(fmaxf(a.z * inv, -127.f), 127.f));
    const int q3 = (int)rintf(fminf(fmaxf(a.w * inv, -127.f), 127.f));
    const uint pack = (uint)(q0 & 255) | ((uint)(q1 & 255) << 8)
                    | ((uint)(q2 & 255) << 16) | ((uint)q3 << 24);
    zq[(size_t)n * 32 + sub] = pack;

    int S = sdot4((int)pack, (int)pack, 0);
    #pragma unroll
    for (int off = 16; off > 0; off >>= 1) S += __shfl_xor(S, off);

    if (sub == 0) {
        float4 mt;
        mt.x = s;
        mt.y = (s * s) * (float)S;   // nrm; edge-side wc uses identical expr
        mt.z = dot + b[0];
        mt.w = 0.f;
        meta[n] = mt;
    }
}

// ---------------- Kernel 2: per-edge, 4-edge ILP ----------------
// R12: R11 proved this kernel is latency-bound (halving waves/CU ~doubled
// phase-2 time). Old version: 1 edge per 4-lane group, only 4 in-flight
// uint4/lane, 20 VGPR (register file idle). New: 4 edges per 4-lane group
// (64 edges/wave), 16 row loads + metas in flight per lane, ~118 VGPR,
// __launch_bounds__(256,4) caps at 128 -> 16 waves/CU.
// Outstanding lines/CU: 32w x 6 -> 16w x 24 = 2x.
// All 4 lanes store (lane sub writes output array sub) - no store divergence.
// dist2 = nrm_i + nrm_j - 2·si·sj·dot (==0 exactly when src==dst).
__global__ __launch_bounds__(256, 4) void edge_kernel(
    const uint* __restrict__ zq, const float4* __restrict__ meta,
    const int* __restrict__ ei, float* __restrict__ out, int E)
{
    const int lane = threadIdx.x & 63;
    const int sub  = lane & 3;
    const int g    = lane >> 2;              // 0..15
    const int base = (blockIdx.x * (blockDim.x >> 6) + (threadIdx.x >> 6)) * 64 + g;

    const int e0 = base, e1 = base + 16, e2 = base + 32, e3 = base + 48;
    const int m  = E - 1;
    const int c0 = e0 <= m ? e0 : m;         // clamped safe indices
    const int c1 = e1 <= m ? e1 : m;
    const int c2 = e2 <= m ? e2 : m;
    const int c3 = e3 <= m ? e3 : m;

    // 8 index loads (same-addr across the 4-lane group -> L1 broadcast)
    const int s0 = ei[c0], d0 = ei[E + c0];
    const int s1 = ei[c1], d1 = ei[E + c1];
    const int s2 = ei[c2], d2 = ei[E + c2];
    const int s3 = ei[c3], d3 = ei[E + c3];

    const uint4* zq4 = (const uint4*)zq;     // row = 8 uint4 (128 B)

    // 16 independent 16 B gathers in flight per lane
    const uint4 A0 = zq4[(size_t)s0 * 8 + sub], A1 = zq4[(size_t)s0 * 8 + sub + 4];
    const uint4 B0 = zq4[(size_t)d0 * 8 + sub], B1 = zq4[(size_t)d0 * 8 + sub + 4];
    const uint4 A2 = zq4[(size_t)s1 * 8 + sub], A3 = zq4[(size_t)s1 * 8 + sub + 4];
    const uint4 B2 = zq4[(size_t)d1 * 8 + sub], B3 = zq4[(size_t)d1 * 8 + sub + 4];
    const uint4 A4 = zq4[(size_t)s2 * 8 + sub], A5 = zq4[(size_t)s2 * 8 + sub + 4];
    const uint4 B4 = zq4[(size_t)d2 * 8 + sub], B5 = zq4[(size_t)d2 * 8 + sub + 4];
    const uint4 A6 = zq4[(size_t)s3 * 8 + sub], A7 = zq4[(size_t)s3 * 8 + sub + 4];
    const uint4 B6 = zq4[(size_t)d3 * 8 + sub], B7 = zq4[(size_t)d3 * 8 + sub + 4];

    // meta: src needs {s,nrm} (float2), dst needs {s,nrm,m} (float4)
    const float2 Pi0 = *(const float2*)(meta + s0); const float4 Pj0 = meta[d0];
    const float2 Pi1 = *(const float2*)(meta + s1); const float4 Pj1 = meta[d1];
    const float2 Pi2 = *(const float2*)(meta + s2); const float4 Pj2 = meta[d2];
    const float2 Pi3 = *(const float2*)(meta + s3); const float4 Pj3 = meta[d3];

    int t0 = sdot4((int)A0.x, (int)B0.x, 0);
    t0 = sdot4((int)A0.y, (int)B0.y, t0); t0 = sdot4((int)A0.z, (int)B0.z, t0);
    t0 = sdot4((int)A0.w, (int)B0.w, t0); t0 = sdot4((int)A1.x, (int)B1.x, t0);
    t0 = sdot4((int)A1.y, (int)B1.y, t0); t0 = sdot4((int)A1.z, (int)B1.z, t0);
    t0 = sdot4((int)A1.w, (int)B1.w, t0);

    int t1 = sdot4((int)A2.x, (int)B2.x, 0);
    t1 = sdot4((int)A2.y, (int)B2.y, t1); t1 = sdot4((int)A2.z, (int)B2.z, t1);
    t1 = sdot4((int)A2.w, (int)B2.w, t1); t1 = sdot4((int)A3.x, (int)B3.x, t1);
    t1 = sdot4((int)A3.y, (int)B3.y, t1); t1 = sdot4((int)A3.z, (int)B3.z, t1);
    t1 = sdot4((int)A3.w, (int)B3.w, t1);

    int t2 = sdot4((int)A4.x, (int)B4.x, 0);
    t2 = sdot4((int)A4.y, (int)B4.y, t2); t2 = sdot4((int)A4.z, (int)B4.z, t2);
    t2 = sdot4((int)A4.w, (int)B4.w, t2); t2 = sdot4((int)A5.x, (int)B5.x, t2);
    t2 = sdot4((int)A5.y, (int)B5.y, t2); t2 = sdot4((int)A5.z, (int)B5.z, t2);
    t2 = sdot4((int)A5.w, (int)B5.w, t2);

    int t3 = sdot4((int)A6.x, (int)B6.x, 0);
    t3 = sdot4((int)A6.y, (int)B6.y, t3); t3 = sdot4((int)A6.z, (int)B6.z, t3);
    t3 = sdot4((int)A6.w, (int)B6.w, t3); t3 = sdot4((int)A7.x, (int)B7.x, t3);
    t3 = sdot4((int)A7.y, (int)B7.y, t3); t3 = sdot4((int)A7.z, (int)B7.z, t3);
    t3 = sdot4((int)A7.w, (int)B7.w, t3);

    // 2-step butterfly within each 4-lane group; all 4 lanes end with full dot
    t0 += __shfl_xor(t0, 1); t0 += __shfl_xor(t0, 2);
    t1 += __shfl_xor(t1, 1); t1 += __shfl_xor(t1, 2);
    t2 += __shfl_xor(t2, 1); t2 += __shfl_xor(t2, 2);
    t3 += __shfl_xor(t3, 1); t3 += __shfl_xor(t3, 2);

    // finals (every lane computes; lane sub stores output array sub)
    float* outp = out + (size_t)sub * E;

    #define FINISH(K, PiK, PjK, tK, eK, cK)                                   \
    {                                                                         \
        const float wc    = (PiK.x * PjK.x) * (float)tK;                      \
        const float dist2 = fmaxf(PiK.y + PjK.y - wc - wc, 0.0f) + EPS;       \
        const float logits = PjK.z - __logf(dist2);                           \
        const float prob   = 1.0f / (1.0f + __expf(-logits));                 \
        const float val = (sub == 0) ? logits                                 \
                        : (sub == 1) ? prob                                   \
                        : (sub == 2) ? PjK.z : dist2;                         \
        if (eK <= m) outp[cK] = val;                                          \
    }

    FINISH(0, Pi0, Pj0, t0, e0, c0)
    FINISH(1, Pi1, Pj1, t1, e1, c1)
    FINISH(2, Pi2, Pj2, t2, e2, c2)
    FINISH(3, Pi3, Pj3, t3, e3, c3)
    #undef FINISH
}

// ---------------- Fallback if ws too small ----------------
__global__ __launch_bounds__(256) void gravity_decoder_fallback(
    const float* __restrict__ z, const int* __restrict__ ei,
    const float* __restrict__ W, const float* __restrict__ b,
    float* __restrict__ out, int E)
{
    const int lane = threadIdx.x & 63;
    const int half = lane >> 5, sub = lane & 31;
    const int e = (blockIdx.x * (blockDim.x >> 6) + (threadIdx.x >> 6)) * 2 + half;
    if (e >= E) return;
    const int src = ei[e], dst = ei[E + e];
    const float4* z4 = (const float4*)z;
    const float4 a = z4[(size_t)src * (D / 4) + sub];
    const float4 c = z4[(size_t)dst * (D / 4) + sub];
    const float4 w = ((const float4*)W)[sub];
    float dot = c.x * w.x + c.y * w.y + c.z * w.z + c.w * w.w;
    const float dx = a.x - c.x, dy = a.y - c.y, dz = a.z - c.z, dw = a.w - c.w;
    float d2 = dx * dx + dy * dy + dz * dz + dw * dw;
    #pragma unroll
    for (int off = 16; off > 0; off >>= 1) {
        dot += __shfl_xor(dot, off);
        d2  += __shfl_xor(d2,  off);
    }
    if (sub == 0) {
        const float mj = dot + b[0];
        const float dist2 = d2 + EPS;
        const float logits = mj - __logf(dist2);
        const float prob = 1.0f / (1.0f + __expf(-logits));
        out[e] = logits; out[E + e] = prob;
        out[2 * E + e] = mj; out[3 * E + e] = dist2;
    }
}

extern "C" void kernel_launch(void* const* d_in, const int* in_sizes, int n_in,
                              void* d_out, int out_size, void* d_ws, size_t ws_size,
                              hipStream_t stream)
{
    const float* z  = (const float*)d_in[0];
    const int*   ei = (const int*)d_in[1];
    const float* W  = (const float*)d_in[2];
    const float* b  = (const float*)d_in[3];
    float* out = (float*)d_out;

    const int E = in_sizes[1] / 2;   // edge_index is [2, E]
    const int N = in_sizes[0] / D;   // z is [N, 128]

    const size_t zq_bytes   = (size_t)N * D;              // i8 rows, 128 B
    const size_t meta_bytes = (size_t)N * sizeof(float4);

    if (ws_size >= zq_bytes + meta_bytes) {
        uint*   zq   = (uint*)d_ws;
        float4* meta = (float4*)((char*)d_ws + zq_bytes);

        const int nodes_per_block = 8;   // 2 nodes/wave x 4 waves
        node_precompute_kernel<<<(N + nodes_per_block - 1) / nodes_per_block,
                                 256, 0, stream>>>(z, W, b, zq, meta, N);

        const int edges_per_block = 256;  // 64 edges/wave x 4 waves
        edge_kernel<<<(E + edges_per_block - 1) / edges_per_block,
                      256, 0, stream>>>(zq, meta, ei, out, E);
    } else {
        const int edges_per_block = 8;
        gravity_decoder_fallback<<<(E + edges_per_block - 1) / edges_per_block,
                                   256, 0, stream>>>(z, ei, W, b, out, E);
    }
}

// Round 3
// 117.434 us; speedup vs baseline: 1.9506x; 1.0434x over previous
//
#include <hip/hip_runtime.h>
#include <math.h>

#define D 128
#define EPS 1e-7f

typedef unsigned int uint;

__device__ __forceinline__ int sdot4(int a, int b, int c) {
#if __has_builtin(__builtin_amdgcn_sdot4)
    return __builtin_amdgcn_sdot4(a, b, c, false);   // v_dot4_i32_i8
#else
    int r = c;
    #pragma unroll
    for (int i = 0; i < 4; ++i) {
        int av = (a << (24 - 8 * i)) >> 24;
        int bv = (b << (24 - 8 * i)) >> 24;
        r += av * bv;
    }
    return r;
#endif
}

// ---------------- Kernel 1: per-node precompute (unchanged, verified) -------
// m[n] = z[n]·W + b (exact f32). q[n] = round(z[n]/s_n) int8, s_n = rowmax/127.
// meta[n] = {s_n, nrm_n = s_n^2·Σq², m_n, 0}. 32 lanes/node, 2 nodes/wave.
// Streaming: ~51 MB read + ~14 MB write ≈ 11 µs HBM floor — near-roofline.
__global__ __launch_bounds__(256) void node_precompute_kernel(
    const float* __restrict__ z, const float* __restrict__ W,
    const float* __restrict__ b,
    uint* __restrict__ zq,        // [N, 32] dwords (128 i8 per row)
    float4* __restrict__ meta, int N)
{
    const int lane = threadIdx.x & 63;
    const int half = lane >> 5, sub = lane & 31;
    const int n = (blockIdx.x * (blockDim.x >> 6) + (threadIdx.x >> 6)) * 2 + half;
    if (n >= N) return;

    const float4 a = ((const float4*)(z + (size_t)n * D))[sub];
    const float4 w = ((const float4*)W)[sub];

    float dot = a.x * w.x + a.y * w.y + a.z * w.z + a.w * w.w;
    float amax = fmaxf(fmaxf(fabsf(a.x), fabsf(a.y)), fmaxf(fabsf(a.z), fabsf(a.w)));
    #pragma unroll
    for (int off = 16; off > 0; off >>= 1) {
        dot  += __shfl_xor(dot, off);
        amax  = fmaxf(amax, __shfl_xor(amax, off));
    }

    const float s   = amax * (1.0f / 127.0f);
    const float inv = 127.0f / fmaxf(amax, 1e-30f);

    const int q0 = (int)rintf(fminf(fmaxf(a.x * inv, -127.f), 127.f));
    const int q1 = (int)rintf(fminf(fmaxf(a.y * inv, -127.f), 127.f));
    const int q2 = (int)rintf(fminf(fmaxf(a.z * inv, -127.f), 127.f));
    const int q3 = (int)rintf(fminf(fmaxf(a.w * inv, -127.f), 127.f));
    const uint pack = (uint)(q0 & 255) | ((uint)(q1 & 255) << 8)
                    | ((uint)(q2 & 255) << 16) | ((uint)q3 << 24);
    zq[(size_t)n * 32 + sub] = pack;

    int S = sdot4((int)pack, (int)pack, 0);
    #pragma unroll
    for (int off = 16; off > 0; off >>= 1) S += __shfl_xor(S, off);

    if (sub == 0) {
        float4 mt;
        mt.x = s;
        mt.y = (s * s) * (float)S;   // nrm; edge-side wc uses identical expr
        mt.z = dot + b[0];
        mt.w = 0.f;
        meta[n] = mt;
    }
}

// ---------------- Kernel 2: per-edge, 8 lanes/row full-line gathers ---------
// R13 history: R11 (16 waves/CU, same per-wave ILP) ~doubled edge time ->
// occupancy is mandatory. R12 (4x ILP at 16 waves/CU) was neutral-to-worse ->
// not outstanding-capacity-bound. Remaining lever: request COUNT. Old: 4-lane
// groups read a 128 B row as 2 x uint4/lane -> 16 x 64 B segments per load
// instruction. New: 8 lanes per row, 1 uint4/lane -> 8 x 128 B FULL-LINE
// segments per instruction (half the TA transactions, every request = exactly
// one aligned L2 line = one zq row). 2 edges per 8-lane group (16 edges/wave,
// same as the 117.7 config), 4 uint4/lane in flight (same MLP), ~52 VGPR,
// __launch_bounds__(256,8) pins the 64-VGPR budget -> 32 waves/CU.
// Store: lane sub8 = (edge sel, array sel) -> 1 fully-active store instr,
// 4 x 64 B segments. dist2 = nrm_i + nrm_j - 2·si·sj·dot (==0 when src==dst).
__global__ __launch_bounds__(256, 8) void edge_kernel(
    const uint* __restrict__ zq, const float4* __restrict__ meta,
    const int* __restrict__ ei, float* __restrict__ out, int E)
{
    const int lane = threadIdx.x & 63;
    const int sub8 = lane & 7;           // 16 B granule within the 128 B row
    const int grp  = lane >> 3;          // 0..7
    const int wid  = blockIdx.x * (blockDim.x >> 6) + (threadIdx.x >> 6);
    const int base = wid * 16;
    const int m    = E - 1;

    const int e0 = base + grp;           // edges 0..7 of this wave's 16
    const int e1 = base + 8 + grp;       // edges 8..15
    const int c0 = e0 <= m ? e0 : m;     // clamped safe indices
    const int c1 = e1 <= m ? e1 : m;

    // index loads: same addr across the 8-lane group -> broadcast;
    // 8 distinct consecutive values per wave instruction (32 B segment)
    const int s0 = ei[c0], d0 = ei[E + c0];
    const int s1 = ei[c1], d1 = ei[E + c1];

    const uint4* zq4 = (const uint4*)zq; // row = 8 uint4 (128 B, line-aligned)

    // 4 full-row gathers in flight per lane; each instruction = 8 whole rows
    const uint4 A0 = zq4[(size_t)s0 * 8 + sub8];
    const uint4 B0 = zq4[(size_t)d0 * 8 + sub8];
    const uint4 A1 = zq4[(size_t)s1 * 8 + sub8];
    const uint4 B1 = zq4[(size_t)d1 * 8 + sub8];

    // meta: src needs {s,nrm}, dst needs {s,nrm,m}; 1.6 MB table, L2-hot
    const float2 Pi0 = *(const float2*)(meta + s0);
    const float4 Pj0 = meta[d0];
    const float2 Pi1 = *(const float2*)(meta + s1);
    const float4 Pj1 = meta[d1];

    int t0 = sdot4((int)A0.x, (int)B0.x, 0);
    t0 = sdot4((int)A0.y, (int)B0.y, t0);
    t0 = sdot4((int)A0.z, (int)B0.z, t0);
    t0 = sdot4((int)A0.w, (int)B0.w, t0);

    int t1 = sdot4((int)A1.x, (int)B1.x, 0);
    t1 = sdot4((int)A1.y, (int)B1.y, t1);
    t1 = sdot4((int)A1.z, (int)B1.z, t1);
    t1 = sdot4((int)A1.w, (int)B1.w, t1);

    // 3-step butterfly within each 8-lane group; all 8 lanes end with full dot
    t0 += __shfl_xor(t0, 1); t0 += __shfl_xor(t0, 2); t0 += __shfl_xor(t0, 4);
    t1 += __shfl_xor(t1, 1); t1 += __shfl_xor(t1, 2); t1 += __shfl_xor(t1, 4);

    // lane sub8 -> (edge select, output-array select)
    const int sel = sub8 >> 2;           // 0: e0, 1: e1
    const int arr = sub8 & 3;            // 0: logits, 1: prob, 2: m_j, 3: dist2

    const float six = sel ? Pi1.x : Pi0.x;
    const float siy = sel ? Pi1.y : Pi0.y;
    const float sjx = sel ? Pj1.x : Pj0.x;
    const float sjy = sel ? Pj1.y : Pj0.y;
    const float sjz = sel ? Pj1.z : Pj0.z;
    const int   td  = sel ? t1 : t0;
    const int   ee  = sel ? e1 : e0;
    const int   ce  = sel ? c1 : c0;

    const float wc     = (six * sjx) * (float)td;
    const float dist2  = fmaxf(siy + sjy - wc - wc, 0.0f) + EPS;
    const float logits = sjz - __logf(dist2);
    const float prob   = 1.0f / (1.0f + __expf(-logits));
    const float val = (arr == 0) ? logits
                    : (arr == 1) ? prob
                    : (arr == 2) ? sjz : dist2;

    // one store instruction: per array, 16 consecutive floats (64 B segment)
    if (ee <= m) out[(size_t)arr * E + ce] = val;
}

// ---------------- Fallback if ws too small ----------------
__global__ __launch_bounds__(256) void gravity_decoder_fallback(
    const float* __restrict__ z, const int* __restrict__ ei,
    const float* __restrict__ W, const float* __restrict__ b,
    float* __restrict__ out, int E)
{
    const int lane = threadIdx.x & 63;
    const int half = lane >> 5, sub = lane & 31;
    const int e = (blockIdx.x * (blockDim.x >> 6) + (threadIdx.x >> 6)) * 2 + half;
    if (e >= E) return;
    const int src = ei[e], dst = ei[E + e];
    const float4* z4 = (const float4*)z;
    const float4 a = z4[(size_t)src * (D / 4) + sub];
    const float4 c = z4[(size_t)dst * (D / 4) + sub];
    const float4 w = ((const float4*)W)[sub];
    float dot = c.x * w.x + c.y * w.y + c.z * w.z + c.w * w.w;
    const float dx = a.x - c.x, dy = a.y - c.y, dz = a.z - c.z, dw = a.w - c.w;
    float d2 = dx * dx + dy * dy + dz * dz + dw * dw;
    #pragma unroll
    for (int off = 16; off > 0; off >>= 1) {
        dot += __shfl_xor(dot, off);
        d2  += __shfl_xor(d2,  off);
    }
    if (sub == 0) {
        const float mj = dot + b[0];
        const float dist2 = d2 + EPS;
        const float logits = mj - __logf(dist2);
        const float prob = 1.0f / (1.0f + __expf(-logits));
        out[e] = logits; out[E + e] = prob;
        out[2 * E + e] = mj; out[3 * E + e] = dist2;
    }
}

extern "C" void kernel_launch(void* const* d_in, const int* in_sizes, int n_in,
                              void* d_out, int out_size, void* d_ws, size_t ws_size,
                              hipStream_t stream)
{
    const float* z  = (const float*)d_in[0];
    const int*   ei = (const int*)d_in[1];
    const float* W  = (const float*)d_in[2];
    const float* b  = (const float*)d_in[3];
    float* out = (float*)d_out;

    const int E = in_sizes[1] / 2;   // edge_index is [2, E]
    const int N = in_sizes[0] / D;   // z is [N, 128]

    const size_t zq_bytes   = (size_t)N * D;              // i8 rows, 128 B
    const size_t meta_bytes = (size_t)N * sizeof(float4);

    if (ws_size >= zq_bytes + meta_bytes) {
        uint*   zq   = (uint*)d_ws;
        float4* meta = (float4*)((char*)d_ws + zq_bytes);

        const int nodes_per_block = 8;   // 2 nodes/wave x 4 waves
        node_precompute_kernel<<<(N + nodes_per_block - 1) / nodes_per_block,
                                 256, 0, stream>>>(z, W, b, zq, meta, N);

        const int edges_per_block = 64;  // 16 edges/wave x 4 waves
        edge_kernel<<<(E + edges_per_block - 1) / edges_per_block,
                      256, 0, stream>>>(zq, meta, ei, out, E);
    } else {
        const int edges_per_block = 8;
        gravity_decoder_fallback<<<(E + edges_per_block - 1) / edges_per_block,
                                   256, 0, stream>>>(z, ei, W, b, out, E);
    }
}